// Round 1
// baseline (267.497 us; speedup 1.0000x reference)
//
#include <hip/hip_runtime.h>

// ---------------- problem constants ----------------
#define N_ANCH 221184      // H*W*A = 128*192*9
#define HW     24576       // H*W
#define Wd     192
#define AA     9
#define TOPN   6000
#define POSTN  300
#define CAND_CAP 8192
#define NWORDS 94          // ceil(6016/64) words of suppression bits
#define NCHUNK 47          // 6016 / 128

typedef unsigned long long u64;

// anchor widths/heights (== ws2/hs2 of the reference, exact small ints)
__device__ const float c_aw[9] = {184.f,368.f,736.f,128.f,256.f,512.f, 88.f,176.f,352.f};
__device__ const float c_ah[9] = { 96.f,192.f,384.f,128.f,256.f,512.f,176.f,352.f,704.f};

// shared box decode — used by decode_kernel AND rank_scatter so the FP
// sequence (and thus every bit of the box) is identical in both places.
__device__ __forceinline__ float4 decode_box(int a, int cell,
                                             const float* __restrict__ deltas,
                                             float info0, float info1, float info2,
                                             bool* valid) {
    int h = cell / Wd;
    int w = cell - h * Wd;
    const float* db = deltas + (size_t)(4 * a) * HW + cell;
    float dx = db[0];
    float dy = db[HW];
    float dw = db[2 * HW];
    float dh = db[3 * HW];
    dw = fminf(fmaxf(dw, -10.f), 10.f);
    dh = fminf(fmaxf(dh, -10.f), 10.f);

    float ww = c_aw[a], hh = c_ah[a];
    float cx = 16.f * (float)w + 8.f;   // exact
    float cy = 16.f * (float)h + 8.f;   // exact

    float pcx = __fadd_rn(__fmul_rn(dx, ww), cx);
    float pcy = __fadd_rn(__fmul_rn(dy, hh), cy);
    float pw  = __fmul_rn(expf(dw), ww);
    float ph  = __fmul_rn(expf(dh), hh);
    float hpw = __fmul_rn(0.5f, pw);
    float hph = __fmul_rn(0.5f, ph);
    float x1 = __fsub_rn(pcx, hpw);
    float x2 = __fadd_rn(pcx, hpw);
    float y1 = __fsub_rn(pcy, hph);
    float y2 = __fadd_rn(pcy, hph);

    float xmax = __fsub_rn(info1, 1.f);
    float ymax = __fsub_rn(info0, 1.f);
    x1 = fminf(fmaxf(x1, 0.f), xmax);
    x2 = fminf(fmaxf(x2, 0.f), xmax);
    y1 = fminf(fmaxf(y1, 0.f), ymax);
    y2 = fminf(fmaxf(y2, 0.f), ymax);

    float msz = __fmul_rn(16.f, info2);
    *valid = (__fadd_rn(__fsub_rn(x2, x1), 1.f) >= msz) &&
             (__fadd_rn(__fsub_rn(y2, y1), 1.f) >= msz);
    return make_float4(x1, y1, x2, y2);
}

// ---------------- init: zero hist256+state+cand (contiguous) + vmask ------
#define ZA_F4 4164    // (1024 + 64 + 65536) / 16
#define ZB_F4 48      // 768 / 16
__global__ __launch_bounds__(256) void init_kernel(float4* zA, float4* zB) {
    int t = blockIdx.x * 256 + threadIdx.x;
    float4 z = make_float4(0.f, 0.f, 0.f, 0.f);
    if (t < ZA_F4) zA[t] = z;
    else if (t < ZA_F4 + ZB_F4) zB[t - ZA_F4] = z;
}

__global__ __launch_bounds__(256) void decode_kernel(const float* __restrict__ scores,
                                                     const float* __restrict__ deltas,
                                                     const float* __restrict__ iminfo,
                                                     unsigned int* __restrict__ keys,
                                                     unsigned int* __restrict__ hist256) {
    __shared__ unsigned int lh[256];
    lh[threadIdx.x] = 0u;
    __syncthreads();
    int t = blockIdx.x * 256 + threadIdx.x;
    int a = t / HW;
    int cell = t - a * HW;
    float score = scores[(AA + a) * HW + cell];
    bool valid;
    (void)decode_box(a, cell, deltas, iminfo[0], iminfo[1], iminfo[2], &valid);
    unsigned int sb = __float_as_uint(score);
    unsigned int key = valid ? ((sb & 0x80000000u) ? ~sb : (sb | 0x80000000u))
                             : 0x007FFFFFu;
    keys[t] = key;
    atomicAdd(&lh[key >> 24], 1u);
    __syncthreads();
    if (lh[threadIdx.x]) atomicAdd(&hist256[threadIdx.x], lh[threadIdx.x]);
}

__global__ __launch_bounds__(1024) void midselect_kernel(const unsigned int* __restrict__ keys,
                                                         const unsigned int* __restrict__ hist256,
                                                         unsigned int* __restrict__ state) {
    __shared__ unsigned int sfx[256];
    __shared__ unsigned int h2w[16][256];
    __shared__ unsigned int sP, sRank;
    int t = threadIdx.x;
    int wv = t >> 6;
    for (int i = t; i < 16 * 256; i += 1024) ((unsigned int*)h2w)[i] = 0u;
    if (t < 256) sfx[t] = hist256[t];
    __syncthreads();
    for (int d = 1; d < 256; d <<= 1) {
        unsigned int v = 0u;
        if (t < 256 && t + d < 256) v = sfx[t + d];
        __syncthreads();
        if (t < 256) sfx[t] += v;
        __syncthreads();
    }
    if (t < 256) {
        unsigned int ge = sfx[t];
        unsigned int gt = (t < 255) ? sfx[t + 1] : 0u;
        if (ge >= TOPN && gt < TOPN) { sP = (unsigned int)t; sRank = TOPN - gt; }
    }
    __syncthreads();
    unsigned int P = sP, rank = sRank;
    const uint4* k4 = (const uint4*)keys;
    for (int i = t; i < N_ANCH / 4; i += 1024) {
        uint4 v = k4[i];
        if ((v.x >> 24) == P) atomicAdd(&h2w[wv][(v.x >> 16) & 0xFFu], 1u);
        if ((v.y >> 24) == P) atomicAdd(&h2w[wv][(v.y >> 16) & 0xFFu], 1u);
        if ((v.z >> 24) == P) atomicAdd(&h2w[wv][(v.z >> 16) & 0xFFu], 1u);
        if ((v.w >> 24) == P) atomicAdd(&h2w[wv][(v.w >> 16) & 0xFFu], 1u);
    }
    __syncthreads();
    if (t < 256) {
        unsigned int s = 0;
        #pragma unroll
        for (int wvi = 0; wvi < 16; ++wvi) s += h2w[wvi][t];
        sfx[t] = s;
    }
    __syncthreads();
    for (int d = 1; d < 256; d <<= 1) {
        unsigned int v = 0u;
        if (t < 256 && t + d < 256) v = sfx[t + d];
        __syncthreads();
        if (t < 256) sfx[t] += v;
        __syncthreads();
    }
    if (t < 256) {
        unsigned int ge = sfx[t];
        unsigned int gt = (t < 255) ? sfx[t + 1] : 0u;
        if (ge >= rank && gt < rank) {
            state[0] = (P << 24) | ((unsigned int)t << 16);
            state[2] = 0u;
        }
    }
}

__global__ __launch_bounds__(256) void compact_kernel(const unsigned int* __restrict__ keys,
                                                      unsigned int* __restrict__ state,
                                                      u64* __restrict__ cand) {
    int t = blockIdx.x * 256 + threadIdx.x;
    unsigned int k = keys[t];
    unsigned int T = state[0];
    if (k >= T) {
        unsigned int pos = atomicAdd(&state[2], 1u);
        if (pos < CAND_CAP) {
            int a = t / HW;
            int cell = t - a * HW;
            unsigned int aidx = (unsigned int)(cell * 9 + a);
            cand[pos] = ((u64)k << 32) | (u64)(~aidx);
        }
    }
}

__global__ __launch_bounds__(256) void rank_scatter_kernel(const u64* __restrict__ cand,
                                                           const float* __restrict__ deltas,
                                                           const float* __restrict__ iminfo,
                                                           float4* __restrict__ tb,
                                                           u64* __restrict__ vmask) {
    __shared__ u64 s[CAND_CAP];
    for (int j = threadIdx.x; j < CAND_CAP; j += 256) s[j] = cand[j];
    int part = threadIdx.x & 7;
    int i = blockIdx.x * 32 + (threadIdx.x >> 3);
    u64 k = cand[i];
    __syncthreads();
    const ulonglong2* sv = (const ulonglong2*)s;
    unsigned int cnt = 0;
    #pragma unroll 8
    for (int jj = part; jj < CAND_CAP / 2; jj += 8) {
        ulonglong2 v = sv[jj];
        cnt += (v.x > k) ? 1u : 0u;
        cnt += (v.y > k) ? 1u : 0u;
    }
    cnt += __shfl_xor(cnt, 1);
    cnt += __shfl_xor(cnt, 2);
    cnt += __shfl_xor(cnt, 4);
    if (part == 0 && k != 0ull && cnt < TOPN) {
        unsigned int aidx = ~((unsigned int)k);
        int a = (int)(aidx % 9u);
        int cell = (int)(aidx / 9u);
        bool valid;
        float4 box = decode_box(a, cell, deltas, iminfo[0], iminfo[1], iminfo[2], &valid);
        tb[cnt] = box;
        if ((unsigned int)(k >> 32) != 0x007FFFFFu)
            atomicOr(&vmask[cnt >> 6], 1ull << (cnt & 63));
    }
}

// suppression bit-matrix, upper-triangle word-blocks only.
__global__ __launch_bounds__(64) void nms_matrix_kernel(const float4* __restrict__ tb,
                                                        u64* __restrict__ mat) {
    if (blockIdx.x < blockIdx.y) return;
    __shared__ float4 cb[64];
    int t = threadIdx.x;
    int c0 = blockIdx.x * 64;
    int col = c0 + t;
    cb[t] = (col < TOPN) ? tb[col] : make_float4(0.f, 0.f, 0.f, 0.f);
    __syncthreads();
    int row = blockIdx.y * 64 + t;
    if (row >= TOPN) return;
    float4 rb = tb[row];
    float rA = (rb.z - rb.x) * (rb.w - rb.y);
    u64 mask = 0ull;
    for (int c = 0; c < 64; ++c) {
        if (c0 + c >= TOPN) break;
        float4 b = cb[c];
        float lx = fmaxf(rb.x, b.x), ly = fmaxf(rb.y, b.y);
        float rx = fminf(rb.z, b.z), ry = fminf(rb.w, b.w);
        float iw = fmaxf(rx - lx, 0.f), ih = fmaxf(ry - ly, 0.f);
        float inter = iw * ih;
        float bA = (b.z - b.x) * (b.w - b.y);
        float iou = inter / ((rA + bA) - inter);
        if (iou > 0.7f) mask |= (1ull << c);
    }
    mat[(size_t)row * NWORDS + blockIdx.x] = mask;
}

// 64-bit readlane with wave-uniform index.
__device__ __forceinline__ u64 rdl64(u64 v, int l) {
    unsigned int lo = (unsigned int)__builtin_amdgcn_readlane((int)(unsigned int)v, l);
    unsigned int hi = (unsigned int)__builtin_amdgcn_readlane((int)(unsigned int)(v >> 32), l);
    return ((u64)hi << 32) | (u64)lo;
}

// Speculative-prefetch slot set: up to 8 candidate rows of the NEXT chunk,
// loaded one chunk early from a SUPERSET of its survivors (removal bits only
// ever get set, so survivors computed one chunk early can only shrink).
// All slot accesses are static-index (full #pragma unroll) — registers only.
struct Spec {
    u64 v0[8];   // row[lane]       (words 0..63 of the row)
    u64 v1[8];   // row[64+lane]    (words 64..93, lanes 0..29)
    u64 m0, m1;  // superset bit mask (bits 0..127 of the chunk), wave-uniform
};

// One 128-box chunk of the greedy scan.
//  - diag (dA,dB): this chunk's 128x128 diagonal bit-block, prefetched 4 deep
//  - in:  speculative rows for THIS chunk (issued one chunk ago)
//  - out: speculative rows for the NEXT chunk (issued here, waited next chunk)
// Returns true when POSTN boxes have been kept (terminate).
__device__ __forceinline__ bool chunk_body(int c, int lane,
                                           const u64* __restrict__ mat,
                                           ulonglong2 dA, ulonglong2 dB,
                                           Spec& in, Spec& out,
                                           u64& r0, u64& r1, int& cnt,
                                           int* kept) {
    const int w2 = 2 * c;
    u64 s0 = (w2 < 64) ? rdl64(r0, w2) : rdl64(r1, w2 - 64);
    u64 s1 = (w2 + 1 < 64) ? rdl64(r0, w2 + 1) : rdl64(r1, w2 + 1 - 64);

    // ---- issue speculative loads for chunk c+1 (branch-free: static vmcnt
    // counts so the compiler can emit counted waits instead of vmcnt(0)) ----
    {
        const int cn = (c + 1 < NCHUNK) ? (c + 1) : (NCHUNK - 1);
        const int w2n = 2 * cn;
        u64 t0 = (w2n < 64) ? rdl64(r0, w2n) : rdl64(r1, w2n - 64);
        u64 t1 = (w2n + 1 < 64) ? rdl64(r0, w2n + 1) : rdl64(r1, w2n + 1 - 64);
        u64 p0 = ~t0, p1 = ~t1;
        out.m0 = p0; out.m1 = p1;
        const int nbase = cn * 128;
        const u64 lmask = (lane < NWORDS - 64) ? ~0ull : 0ull;
        const int l1 = (lane < NWORDS - 64) ? (64 + lane) : 63;
        u64 mm0 = p0, mm1 = p1;
        #pragma unroll
        for (int j = 0; j < 8; ++j) {
            int b = -1;
            if (mm0)      { b = __ffsll(mm0) - 1;      mm0 &= mm0 - 1; }
            else if (mm1) { b = 64 + __ffsll(mm1) - 1; mm1 &= mm1 - 1; }
            int bS = (b >= 0) ? b : 0;
            const u64* row = mat + (size_t)(nbase + bS) * NWORDS;
            u64 x0 = row[lane];
            u64 x1 = row[l1];
            u64 live = (b >= 0) ? ~0ull : 0ull;
            out.v0[j] = x0 & live;
            out.v1[j] = x1 & live & lmask;
        }
    }

    // ---- greedy within the chunk (registers + readlane only) ----
    if ((s0 & s1) != ~0ull) {
        const int base = c * 128;
        u64 rem0 = s0, rem1 = s1, k0 = 0ull, k1 = 0ull;
        while (cnt < POSTN) {
            int b;
            if (~rem0)      b = __ffsll((u64)~rem0) - 1;
            else if (~rem1) b = 64 + __ffsll((u64)~rem1) - 1;
            else break;
            if (lane == 0) kept[cnt] = base + b;
            ++cnt;
            if (b < 64) {
                rem0 |= rdl64(dA.x, b);
                rem1 |= rdl64(dA.y, b);
                k0 |= 1ull << b; rem0 |= 1ull << b;
            } else {
                int bb = b - 64;
                rem0 |= rdl64(dB.x, bb);
                rem1 |= rdl64(dB.y, bb);
                k1 |= 1ull << bb; rem1 |= 1ull << bb;
            }
        }
        if (cnt >= POSTN) return true;

        // ---- propagation: OR kept rows into removal bitmap ----
        if (k0 | k1) {
            // slots covered by the speculative set issued one chunk ago
            u64 mm0 = in.m0, mm1 = in.m1, cov0 = 0ull, cov1 = 0ull;
            u64 f0 = 0ull, f1 = 0ull;
            #pragma unroll
            for (int j = 0; j < 8; ++j) {
                int b = -1;
                if (mm0)      { b = __ffsll(mm0) - 1;      mm0 &= mm0 - 1; }
                else if (mm1) { b = 64 + __ffsll(mm1) - 1; mm1 &= mm1 - 1; }
                if (b >= 0) {
                    u64 kj;
                    if (b < 64) { kj = (k0 >> b) & 1ull;        cov0 |= 1ull << b; }
                    else        { kj = (k1 >> (b - 64)) & 1ull; cov1 |= 1ull << (b - 64); }
                    u64 msk = 0ull - kj;
                    f0 |= in.v0[j] & msk;
                    f1 |= in.v1[j] & msk;
                }
            }
            // leftovers (superset truncated / chunk 0): dependent batch load
            u64 lk0 = k0 & ~cov0, lk1 = k1 & ~cov1;
            if (lk0 | lk1) {
                u64 m0 = lk0, m1 = lk1;
                while (m0 | m1) {
                    int idxs[8];
                    #pragma unroll
                    for (int j = 0; j < 8; ++j) {
                        int b = -1;
                        if (m0)      { b = __ffsll(m0) - 1;      m0 &= m0 - 1; }
                        else if (m1) { b = 64 + __ffsll(m1) - 1; m1 &= m1 - 1; }
                        idxs[j] = b;
                    }
                    u64 v0[8], v1[8];
                    #pragma unroll
                    for (int j = 0; j < 8; ++j) {
                        v0[j] = 0ull; v1[j] = 0ull;
                        if (idxs[j] >= 0) {
                            const u64* row = mat + (size_t)(base + idxs[j]) * NWORDS;
                            v0[j] = row[lane];
                            if (lane < NWORDS - 64) v1[j] = row[64 + lane];
                        }
                    }
                    #pragma unroll
                    for (int j = 0; j < 8; ++j) { f0 |= v0[j]; f1 |= v1[j]; }
                }
            }
            r0 |= f0; r1 |= f1;
        }
    }
    return false;
}

// load diag pair for chunk cc (clamped — out-of-range loads are harmless
// re-reads of chunk 46, keeping the VMEM issue count static for waitcnt).
#define LDIAG(cc, A, B) do {                                                  \
    int c_ = (cc) < NCHUNK ? (cc) : (NCHUNK - 1);                             \
    const u64* pA_ = mat + (size_t)(c_ * 128 + lane) * NWORDS + 2 * c_;       \
    const u64* pB_ = mat + (size_t)(c_ * 128 + 64 + lane) * NWORDS + 2 * c_;  \
    A = *(const ulonglong2*)pA_; B = *(const ulonglong2*)pB_; } while (0)

// single-wave greedy scan, 128-box chunks.
//  - diagonal bit-blocks prefetched FOUR chunks ahead (group-of-4, named regs)
//  - suppression rows prefetched ONE chunk ahead from a survivor superset
__global__ __launch_bounds__(64) void nms_scan_kernel(const u64* __restrict__ mat,
                                                      const u64* __restrict__ vmask,
                                                      const float4* __restrict__ tb,
                                                      float* __restrict__ out) {
    int lane = threadIdx.x;
    u64 r0 = ~vmask[lane];
    u64 r1 = (lane < NWORDS - 64) ? ~vmask[64 + lane] : ~0ull;
    __shared__ int kept[POSTN];
    int cnt = 0;

    ulonglong2 z2; z2.x = 0ull; z2.y = 0ull;
    ulonglong2 cA0, cB0, cA1, cB1, cA2, cB2, cA3, cB3;
    LDIAG(0, cA0, cB0); LDIAG(1, cA1, cB1);
    LDIAG(2, cA2, cB2); LDIAG(3, cA3, cB3);

    Spec S0, S1;
    S0.m0 = S0.m1 = 0ull; S1.m0 = S1.m1 = 0ull;
    #pragma unroll
    for (int j = 0; j < 8; ++j) { S0.v0[j] = S0.v1[j] = S1.v0[j] = S1.v1[j] = 0ull; }

    bool done = false;
    for (int g = 0; g < 12 && !done; ++g) {
        int cb = g * 4;
        ulonglong2 nA0 = z2, nB0 = z2, nA1 = z2, nB1 = z2;
        ulonglong2 nA2 = z2, nB2 = z2, nA3 = z2, nB3 = z2;
        LDIAG(cb + 4, nA0, nB0); LDIAG(cb + 5, nA1, nB1);
        LDIAG(cb + 6, nA2, nB2); LDIAG(cb + 7, nA3, nB3);

        done = chunk_body(cb, lane, mat, cA0, cB0, S0, S1, r0, r1, cnt, kept);
        if (!done && cb + 1 < NCHUNK)
            done = chunk_body(cb + 1, lane, mat, cA1, cB1, S1, S0, r0, r1, cnt, kept);
        if (!done && cb + 2 < NCHUNK)
            done = chunk_body(cb + 2, lane, mat, cA2, cB2, S0, S1, r0, r1, cnt, kept);
        if (!done && cb + 3 < NCHUNK)
            done = chunk_body(cb + 3, lane, mat, cA3, cB3, S1, S0, r0, r1, cnt, kept);

        cA0 = nA0; cB0 = nB0; cA1 = nA1; cB1 = nB1;
        cA2 = nA2; cB2 = nB2; cA3 = nA3; cB3 = nB3;
    }

    for (int r = lane; r < POSTN; r += 64) {
        float4 b = make_float4(0.f, 0.f, 0.f, 0.f);
        if (r < cnt) b = tb[kept[r]];
        float* o = out + r * 5;
        o[0] = 0.f; o[1] = b.x; o[2] = b.y; o[3] = b.z; o[4] = b.w;
    }
}

// ---------------- host launcher ----------------
extern "C" void kernel_launch(void* const* d_in, const int* in_sizes, int n_in,
                              void* d_out, int out_size, void* d_ws, size_t ws_size,
                              hipStream_t stream) {
    const float* scores = (const float*)d_in[0];
    const float* deltas = (const float*)d_in[1];
    const float* iminfo = (const float*)d_in[2];
    float* out = (float*)d_out;

    char* ws = (char*)d_ws;
    unsigned int* keys    = (unsigned int*)(ws + 0);          // 221184*4  = 884736
    unsigned int* hist256 = (unsigned int*)(ws + 884736);     // 256*4     = 1024
    unsigned int* state   = (unsigned int*)(ws + 885760);     // 64
    u64*          cand    = (u64*)(ws + 885824);              // 8192*8    = 65536
    float4*       tb      = (float4*)(ws + 951360);           // 6016*16   = 96256
    u64*          vmask   = (u64*)(ws + 1047616);             // 768
    u64*          mat     = (u64*)(ws + 1048384);             // 6016*94*8 = 4524032

    const int NB = N_ANCH / 256;   // 864 exactly

    init_kernel<<<17, 256, 0, stream>>>((float4*)hist256, (float4*)vmask);
    decode_kernel<<<NB, 256, 0, stream>>>(scores, deltas, iminfo, keys, hist256);
    midselect_kernel<<<1, 1024, 0, stream>>>(keys, hist256, state);
    compact_kernel<<<NB, 256, 0, stream>>>(keys, state, cand);
    rank_scatter_kernel<<<CAND_CAP / 32, 256, 0, stream>>>(cand, deltas, iminfo, tb, vmask);
    nms_matrix_kernel<<<dim3(NWORDS, NWORDS), 64, 0, stream>>>(tb, mat);
    nms_scan_kernel<<<1, 64, 0, stream>>>(mat, vmask, tb, out);
}